// Round 6
// baseline (628.935 us; speedup 1.0000x reference)
//
#include <hip/hip_runtime.h>
#include <math.h>

#define NLAYER 4
#define DMODEL 640
#define DINNER 1280
#define DSTATE 16
#define DTRANK 40
#define DCONV  4
#define BATCH  64
#define SEQ    30
#define MTOK   (BATCH*SEQ)       // 1920
#define NPROJ  (2*DINNER)        // 2560
#define NDBL   (DTRANK+2*DSTATE) // 72
#define NDBLP  80                // padded N for x_proj MFMA
#define KSEGS  4
#define KSEG   (DINNER/KSEGS)    // 320

typedef unsigned short u16;
typedef __bf16 bf16x8 __attribute__((ext_vector_type(8)));
typedef float  f32x4  __attribute__((ext_vector_type(4)));

__device__ __forceinline__ float siluf(float x) {
    return x / (1.0f + __expf(-x));
}

__device__ __forceinline__ u16 f2bf(float f) {
    unsigned int u = __float_as_uint(f);
    u += 0x7fffu + ((u >> 16) & 1u);
    return (u16)(u >> 16);
}

__device__ __forceinline__ float bf2f(u16 b) {
    return __uint_as_float(((unsigned int)b) << 16);
}

// h[b,v,:] = x[b,(v + SEQ - vs[b]) % SEQ, :]
__global__ void k_permute(const float* __restrict__ x, const int* __restrict__ vs,
                          float* __restrict__ h) {
    int idx = blockIdx.x * blockDim.x + threadIdx.x;
    if (idx >= MTOK * DMODEL) return;
    int d  = idx % DMODEL;
    int mv = idx / DMODEL;
    int v  = mv % SEQ;
    int b  = mv / SEQ;
    int src = (v + SEQ - vs[b]) % SEQ;
    h[idx] = x[(b * SEQ + src) * DMODEL + d];
}

// fp32 -> bf16, 4/thread
__global__ void k_f2bf(const float* __restrict__ src, u16* __restrict__ dst, int n) {
    int i = (blockIdx.x * blockDim.x + threadIdx.x) * 4;
    if (i >= n) return;
    float4 v = *(const float4*)(src + i);
    ushort4 o;
    o.x = f2bf(v.x); o.y = f2bf(v.y); o.z = f2bf(v.z); o.w = f2bf(v.w);
    *(ushort4*)(dst + i) = o;
}

// xp_w [4][72][1280] fp32 -> [4][80][1280] bf16, rows 72..79 of each layer zeroed
__global__ void k_f2bf_pad4(const float* __restrict__ src, u16* __restrict__ dst) {
    int i = (blockIdx.x * blockDim.x + threadIdx.x) * 4;
    if (i >= NLAYER * NDBLP * DINNER) return;
    int layer = i / (NDBLP * DINNER);
    int rem   = i % (NDBLP * DINNER);
    int row   = rem / DINNER;
    int col   = rem % DINNER;
    ushort4 o = make_ushort4(0, 0, 0, 0);
    if (row < NDBL) {
        float4 v = *(const float4*)(src + (size_t)layer * NDBL * DINNER
                                        + (size_t)row * DINNER + col);
        o.x = f2bf(v.x); o.y = f2bf(v.y); o.z = f2bf(v.z); o.w = f2bf(v.w);
    }
    *(ushort4*)(dst + i) = o;
}

// one wave per token: xn_bf16 = h * rsqrt(mean(h^2)+eps) * w
__global__ __launch_bounds__(64)
void k_rmsnorm(const float* __restrict__ h, const float* __restrict__ w,
               u16* __restrict__ xn) {
    int m = blockIdx.x;
    int t = threadIdx.x;
    const float* row = h + (size_t)m * DMODEL;
    float ss = 0.f;
    for (int d = t; d < DMODEL; d += 64) { float v = row[d]; ss += v * v; }
    #pragma unroll
    for (int o = 32; o > 0; o >>= 1) ss += __shfl_xor(ss, o, 64);
    float sc = rsqrtf(ss / DMODEL + 1e-5f);
    u16* out = xn + (size_t)m * DMODEL;
    for (int d = t; d < DMODEL; d += 64) out[d] = f2bf(row[d] * sc * w[d]);
}

// 128x128-tile bf16 MFMA GEMM: out[m,n] = sum_k A[m,k]*W[n,k].
// If Cb != nullptr writes bf16 to Cb, else f32 (+resid) to Cf.
__global__ __launch_bounds__(256)
void k_mfma(const u16* __restrict__ A, int lda,
            const u16* __restrict__ W,
            const float* __restrict__ resid,
            float* __restrict__ Cf, u16* __restrict__ Cb,
            int N, int K) {
    __shared__ u16 As[128 * 32];
    __shared__ u16 Bs[128 * 32];
    const int t = threadIdx.x;
    const int w = t >> 6, l = t & 63;
    const int lane15 = l & 15, quad = l >> 4;
    const int wm = w >> 1, wn = w & 1;
    const int m0 = blockIdx.y * 128, n0 = blockIdx.x * 128;

    f32x4 acc[4][4];
    #pragma unroll
    for (int i = 0; i < 4; ++i)
        #pragma unroll
        for (int j = 0; j < 4; ++j)
            acc[i][j] = (f32x4){0.f, 0.f, 0.f, 0.f};

    for (int k0 = 0; k0 < K; k0 += 32) {
        __syncthreads();
        #pragma unroll
        for (int q = 0; q < 2; ++q) {
            int c = q * 256 + t;
            const u16* ga = A + (size_t)(m0 + (c >> 2)) * lda + k0 + (c & 3) * 8;
            __builtin_amdgcn_global_load_lds(
                (const __attribute__((address_space(1))) void*)ga,
                (__attribute__((address_space(3))) void*)&As[c * 8], 16, 0, 0);
            const u16* gb = W + (size_t)(n0 + (c >> 2)) * K + k0 + (c & 3) * 8;
            __builtin_amdgcn_global_load_lds(
                (const __attribute__((address_space(1))) void*)gb,
                (__attribute__((address_space(3))) void*)&Bs[c * 8], 16, 0, 0);
        }
        __syncthreads();

        bf16x8 af[4], bfrag[4];
        #pragma unroll
        for (int i = 0; i < 4; ++i)
            af[i] = *(const bf16x8*)&As[(wm * 64 + i * 16 + lane15) * 32 + quad * 8];
        #pragma unroll
        for (int j = 0; j < 4; ++j)
            bfrag[j] = *(const bf16x8*)&Bs[(wn * 64 + j * 16 + lane15) * 32 + quad * 8];
        #pragma unroll
        for (int i = 0; i < 4; ++i)
            #pragma unroll
            for (int j = 0; j < 4; ++j)
                acc[i][j] = __builtin_amdgcn_mfma_f32_16x16x32_bf16(
                    af[i], bfrag[j], acc[i][j], 0, 0, 0);
    }

    #pragma unroll
    for (int i = 0; i < 4; ++i) {
        #pragma unroll
        for (int r = 0; r < 4; ++r) {
            int row = m0 + wm * 64 + i * 16 + quad * 4 + r;
            #pragma unroll
            for (int j = 0; j < 4; ++j) {
                int col = n0 + wn * 64 + j * 16 + lane15;
                size_t idx = (size_t)row * N + col;
                if (Cb) {
                    Cb[idx] = f2bf(acc[i][j][r]);
                } else {
                    float v = acc[i][j][r];
                    if (resid) v += resid[idx];
                    Cf[idx] = v;
                }
            }
        }
    }
}

// 64x64-tile bf16 MFMA GEMM, f32 out + resid (out_proj)
__global__ __launch_bounds__(256)
void k_mfma64(const u16* __restrict__ A, int lda,
              const u16* __restrict__ W,
              const float* __restrict__ resid,
              float* __restrict__ C, int N, int K) {
    __shared__ u16 As[64 * 32];
    __shared__ u16 Bs[64 * 32];
    const int t = threadIdx.x;
    const int w = t >> 6, l = t & 63;
    const int lane15 = l & 15, quad = l >> 4;
    const int wm = w >> 1, wn = w & 1;
    const int m0 = blockIdx.y * 64, n0 = blockIdx.x * 64;

    f32x4 acc[2][2];
    #pragma unroll
    for (int i = 0; i < 2; ++i)
        #pragma unroll
        for (int j = 0; j < 2; ++j)
            acc[i][j] = (f32x4){0.f, 0.f, 0.f, 0.f};

    for (int k0 = 0; k0 < K; k0 += 32) {
        __syncthreads();
        {
            int c = t;
            const u16* ga = A + (size_t)(m0 + (c >> 2)) * lda + k0 + (c & 3) * 8;
            __builtin_amdgcn_global_load_lds(
                (const __attribute__((address_space(1))) void*)ga,
                (__attribute__((address_space(3))) void*)&As[c * 8], 16, 0, 0);
            const u16* gb = W + (size_t)(n0 + (c >> 2)) * K + k0 + (c & 3) * 8;
            __builtin_amdgcn_global_load_lds(
                (const __attribute__((address_space(1))) void*)gb,
                (__attribute__((address_space(3))) void*)&Bs[c * 8], 16, 0, 0);
        }
        __syncthreads();

        bf16x8 af[2], bfrag[2];
        #pragma unroll
        for (int i = 0; i < 2; ++i)
            af[i] = *(const bf16x8*)&As[(wm * 32 + i * 16 + lane15) * 32 + quad * 8];
        #pragma unroll
        for (int j = 0; j < 2; ++j)
            bfrag[j] = *(const bf16x8*)&Bs[(wn * 32 + j * 16 + lane15) * 32 + quad * 8];
        #pragma unroll
        for (int i = 0; i < 2; ++i)
            #pragma unroll
            for (int j = 0; j < 2; ++j)
                acc[i][j] = __builtin_amdgcn_mfma_f32_16x16x32_bf16(
                    af[i], bfrag[j], acc[i][j], 0, 0, 0);
    }

    #pragma unroll
    for (int i = 0; i < 2; ++i) {
        #pragma unroll
        for (int r = 0; r < 4; ++r) {
            int row = m0 + wm * 32 + i * 16 + quad * 4 + r;
            #pragma unroll
            for (int j = 0; j < 2; ++j) {
                int col = n0 + wn * 32 + j * 16 + lane15;
                size_t idx = (size_t)row * N + col;
                float v = acc[i][j][r];
                if (resid) v += resid[idx];
                C[idx] = v;
            }
        }
    }
}

// causal depthwise conv + silu: one thread per (b,c); bf16 in/out
__global__ __launch_bounds__(256)
void k_conv(const u16* __restrict__ urb, const float* __restrict__ cw,
            const float* __restrict__ cb, u16* __restrict__ ubf) {
    int idx = blockIdx.x * 256 + threadIdx.x;   // b*DINNER + c
    int c = idx % DINNER;
    int b = idx / DINNER;
    const u16* up = urb + (size_t)(b * SEQ) * NPROJ + c;
    float xv[SEQ];
    #pragma unroll
    for (int v = 0; v < SEQ; ++v) xv[v] = bf2f(up[(size_t)v * NPROJ]);
    float w0 = cw[c * 4 + 0], w1 = cw[c * 4 + 1];
    float w2 = cw[c * 4 + 2], w3 = cw[c * 4 + 3];
    float bias = cb[c];
    u16* op = ubf + (size_t)(b * SEQ) * DINNER + c;
    float x0 = 0.f, x1 = 0.f, x2 = 0.f;
    #pragma unroll
    for (int v = 0; v < SEQ; ++v) {
        float x3 = xv[v];
        float o = bias + w0 * x0 + w1 * x1 + w2 * x2 + w3 * x3;
        op[(size_t)v * DINNER] = f2bf(siluf(o));
        x0 = x1; x1 = x2; x2 = x3;
    }
}

// x_proj: split-K bf16 MFMA. A=ubf [MTOK,DINNER], B=wbx [80,DINNER].
// Grid (KSEGS, MTOK/64), 256 thr. Writes fp32 partials dblp[seg][MTOK][80].
__global__ __launch_bounds__(256)
void k_xproj(const u16* __restrict__ ubf, const u16* __restrict__ wbx,
             float* __restrict__ dblp) {
    __shared__ u16 As[64 * 32];
    __shared__ u16 Bs[NDBLP * 32];
    const int t = threadIdx.x;
    const int w = t >> 6, l = t & 63;
    const int lane15 = l & 15, quad = l >> 4;
    const int seg = blockIdx.x;
    const int m0 = blockIdx.y * 64;
    const int kb = seg * KSEG;

    f32x4 acc[5];
    #pragma unroll
    for (int j = 0; j < 5; ++j) acc[j] = (f32x4){0.f, 0.f, 0.f, 0.f};

    for (int k0 = 0; k0 < KSEG; k0 += 32) {
        __syncthreads();
        {
            int c = t;
            const u16* ga = ubf + (size_t)(m0 + (c >> 2)) * DINNER + kb + k0 + (c & 3) * 8;
            __builtin_amdgcn_global_load_lds(
                (const __attribute__((address_space(1))) void*)ga,
                (__attribute__((address_space(3))) void*)&As[c * 8], 16, 0, 0);
            const u16* gb = wbx + (size_t)(c >> 2) * DINNER + kb + k0 + (c & 3) * 8;
            __builtin_amdgcn_global_load_lds(
                (const __attribute__((address_space(1))) void*)gb,
                (__attribute__((address_space(3))) void*)&Bs[c * 8], 16, 0, 0);
        }
        if (t < 64) {
            int c = 256 + t;
            const u16* gb = wbx + (size_t)(c >> 2) * DINNER + kb + k0 + (c & 3) * 8;
            __builtin_amdgcn_global_load_lds(
                (const __attribute__((address_space(1))) void*)gb,
                (__attribute__((address_space(3))) void*)&Bs[c * 8], 16, 0, 0);
        }
        __syncthreads();

        bf16x8 af = *(const bf16x8*)&As[(w * 16 + lane15) * 32 + quad * 8];
        #pragma unroll
        for (int j = 0; j < 5; ++j) {
            bf16x8 bfrag = *(const bf16x8*)&Bs[(j * 16 + lane15) * 32 + quad * 8];
            acc[j] = __builtin_amdgcn_mfma_f32_16x16x32_bf16(af, bfrag, acc[j], 0, 0, 0);
        }
    }

    float* outp = dblp + (size_t)seg * MTOK * NDBLP;
    #pragma unroll
    for (int r = 0; r < 4; ++r) {
        int row = m0 + w * 16 + quad * 4 + r;
        #pragma unroll
        for (int j = 0; j < 5; ++j) {
            int col = j * 16 + lane15;
            outp[(size_t)row * NDBLP + col] = acc[j][r];
        }
    }
}

// Fused dt + selective scan, 4-way lane split per channel.
// Thread quad (lanes sx=0..3) shares one (b,d): each lane owns 10 dt-dot terms
// and 4 of the 16 states; quad shuffle-reduce combines dot and ya sums.
// Grid: BATCH * (DINNER/64) = 1280 blocks x 256 thr (4 waves) -> 20 waves/CU.
__global__ __launch_bounds__(256)
void k_dtscan(const u16* __restrict__ ubf, const u16* __restrict__ urb,
              const float* __restrict__ dblp,
              const float* __restrict__ dtw, const float* __restrict__ dtb,
              const float* __restrict__ A_log, const float* __restrict__ Dsk,
              u16* __restrict__ y) {
    __shared__ float dtL[SEQ][NDBL];   // [30][72]
    const int b  = blockIdx.x / (DINNER / 64);
    const int dc = blockIdx.x % (DINNER / 64);
    const int tid = threadIdx.x;
    const int dl = tid >> 2, sx = tid & 3;
    const int d  = dc * 64 + dl;

    // stage summed dbl tile (sum the KSEGS split-K partials)
    for (int t = tid; t < SEQ * NDBL; t += 256) {
        int v = t / NDBL, col = t % NDBL;
        float s = 0.f;
        #pragma unroll
        for (int sg = 0; sg < KSEGS; ++sg)
            s += dblp[(size_t)sg * MTOK * NDBLP + (size_t)(b * SEQ + v) * NDBLP + col];
        dtL[v][col] = s;
    }
    __syncthreads();

    float dtwr[10];
    #pragma unroll
    for (int r = 0; r < 10; ++r)
        dtwr[r] = dtw[(size_t)d * DTRANK + sx * 10 + r];
    float bias = dtb[d];
    float Ar[4];
    #pragma unroll
    for (int s = 0; s < 4; ++s)
        Ar[s] = -__expf(A_log[(size_t)d * DSTATE + sx * 4 + s]);
    float dsk = Dsk[d];
    float st[4] = {0.f, 0.f, 0.f, 0.f};

    const u16* up = ubf + (size_t)(b * SEQ) * DINNER + d;
    const u16* rp = urb + (size_t)(b * SEQ) * NPROJ + DINNER + d;
    u16* yp = y + (size_t)(b * SEQ) * DINNER + d;

    for (int v = 0; v < SEQ; ++v) {
        // split dt-dot: 10 terms per lane, quad-reduce
        const float* drow = &dtL[v][sx * 10];
        float accp = 0.f;
        #pragma unroll
        for (int r = 0; r < 10; ++r) accp += drow[r] * dtwr[r];
        accp += __shfl_xor(accp, 1, 64);
        accp += __shfl_xor(accp, 2, 64);
        float acc = accp + bias;
        float dlt = (acc > 20.f) ? acc : log1pf(__expf(acc));

        float uu  = bf2f(up[(size_t)v * DINNER]);
        float du  = dlt * uu;
        const float* Bp = &dtL[v][DTRANK + sx * 4];
        const float* Cp = &dtL[v][DTRANK + DSTATE + sx * 4];
        float yap = 0.f;
        #pragma unroll
        for (int s = 0; s < 4; ++s) {
            float dA = __expf(dlt * Ar[s]);
            st[s] = dA * st[s] + du * Bp[s];
            yap += st[s] * Cp[s];
        }
        yap += __shfl_xor(yap, 1, 64);
        yap += __shfl_xor(yap, 2, 64);
        if (sx == 0) {
            float res = bf2f(rp[(size_t)v * NPROJ]);
            yp[(size_t)v * DINNER] = f2bf((yap + uu * dsk) * siluf(res));
        }
    }
}

// final rmsnorm fused with reverse permutation
__global__ __launch_bounds__(64)
void k_final(const float* __restrict__ h, const int* __restrict__ vs,
             const float* __restrict__ w, float* __restrict__ out) {
    int mv = blockIdx.x;
    int v = mv % SEQ, b = mv / SEQ;
    int src = (v + vs[b]) % SEQ;
    const float* row = h + (size_t)(b * SEQ + src) * DMODEL;
    int t = threadIdx.x;
    float ss = 0.f;
    for (int d = t; d < DMODEL; d += 64) { float x = row[d]; ss += x * x; }
    #pragma unroll
    for (int o = 32; o > 0; o >>= 1) ss += __shfl_xor(ss, o, 64);
    float sc = rsqrtf(ss / DMODEL + 1e-5f);
    float* op = out + (size_t)mv * DMODEL;
    for (int d = t; d < DMODEL; d += 64) op[d] = row[d] * sc * w[d];
}

extern "C" void kernel_launch(void* const* d_in, const int* in_sizes, int n_in,
                              void* d_out, int out_size, void* d_ws, size_t ws_size,
                              hipStream_t stream) {
    const float* x      = (const float*)d_in[0];
    const int*   vs     = (const int*)d_in[1];
    const float* norm_w = (const float*)d_in[2];
    const float* in_w   = (const float*)d_in[3];
    const float* conv_w = (const float*)d_in[4];
    const float* conv_b = (const float*)d_in[5];
    const float* xp_w   = (const float*)d_in[6];
    const float* dt_w   = (const float*)d_in[7];
    const float* dt_b   = (const float*)d_in[8];
    const float* A_log  = (const float*)d_in[9];
    const float* Dsk    = (const float*)d_in[10];
    const float* out_w  = (const float*)d_in[11];
    const float* nfw    = (const float*)d_in[12];
    float* out = (float*)d_out;

    char* p = (char*)d_ws;
    float* h    = (float*)p; p += (size_t)MTOK * DMODEL * 4;
    u16*   xn   = (u16*)p;   p += (size_t)MTOK * DMODEL * 2;
    u16*   urb  = (u16*)p;   p += (size_t)MTOK * NPROJ * 2;
    u16*   ubf  = (u16*)p;   p += (size_t)MTOK * DINNER * 2;
    float* dblp = (float*)p; p += (size_t)KSEGS * MTOK * NDBLP * 4;
    u16*   y    = (u16*)p;   p += (size_t)MTOK * DINNER * 2;
    u16*   wbi4 = (u16*)p;   p += (size_t)NLAYER * NPROJ * DMODEL * 2;
    u16*   wbo4 = (u16*)p;   p += (size_t)NLAYER * DMODEL * DINNER * 2;
    u16*   wbx4 = (u16*)p;   p += (size_t)NLAYER * NDBLP * DINNER * 2;

    // hoisted weight conversions (once per call)
    k_f2bf<<<(NLAYER * NPROJ * DMODEL / 4 + 255) / 256, 256, 0, stream>>>(
        in_w, wbi4, NLAYER * NPROJ * DMODEL);
    k_f2bf<<<(NLAYER * DMODEL * DINNER / 4 + 255) / 256, 256, 0, stream>>>(
        out_w, wbo4, NLAYER * DMODEL * DINNER);
    k_f2bf_pad4<<<(NLAYER * NDBLP * DINNER / 4 + 255) / 256, 256, 0, stream>>>(
        xp_w, wbx4);

    k_permute<<<(MTOK * DMODEL + 255) / 256, 256, 0, stream>>>(x, vs, h);

    for (int l = 0; l < NLAYER; ++l) {
        k_rmsnorm<<<MTOK, 64, 0, stream>>>(h, norm_w + (size_t)l * DMODEL, xn);

        k_mfma<<<dim3(NPROJ / 128, MTOK / 128), 256, 0, stream>>>(
            xn, DMODEL, wbi4 + (size_t)l * NPROJ * DMODEL, nullptr,
            nullptr, urb, NPROJ, DMODEL);

        k_conv<<<BATCH * DINNER / 256, 256, 0, stream>>>(
            urb, conv_w + (size_t)l * DINNER * DCONV, conv_b + (size_t)l * DINNER, ubf);

        k_xproj<<<dim3(KSEGS, MTOK / 64), 256, 0, stream>>>(
            ubf, wbx4 + (size_t)l * NDBLP * DINNER, dblp);

        k_dtscan<<<BATCH * (DINNER / 64), 256, 0, stream>>>(
            ubf, urb, dblp,
            dt_w + (size_t)l * DINNER * DTRANK, dt_b + (size_t)l * DINNER,
            A_log + (size_t)l * DINNER * DSTATE, Dsk + (size_t)l * DINNER, y);

        k_mfma64<<<dim3(DMODEL / 64, MTOK / 64), 256, 0, stream>>>(
            y, DINNER, wbo4 + (size_t)l * DMODEL * DINNER, h, h, DMODEL, DINNER);
    }

    k_final<<<MTOK, 64, 0, stream>>>(h, vs, nfw, out);
}

// Round 7
// 526.862 us; speedup vs baseline: 1.1937x; 1.1937x over previous
//
#include <hip/hip_runtime.h>
#include <math.h>

#define NLAYER 4
#define DMODEL 640
#define DINNER 1280
#define DSTATE 16
#define DTRANK 40
#define DCONV  4
#define BATCH  64
#define SEQ    30
#define MTOK   (BATCH*SEQ)       // 1920
#define NPROJ  (2*DINNER)        // 2560
#define NDBL   (DTRANK+2*DSTATE) // 72
#define NDBLP  80                // padded N for x_proj MFMA
#define KSEGS  4
#define KSEG   (DINNER/KSEGS)    // 320
#define DTKP   64                // padded K for dt GEMM

typedef unsigned short u16;
typedef __bf16 bf16x8 __attribute__((ext_vector_type(8)));
typedef float  f32x4  __attribute__((ext_vector_type(4)));

__device__ __forceinline__ float siluf(float x) {
    return x / (1.0f + __expf(-x));
}

__device__ __forceinline__ u16 f2bf(float f) {
    unsigned int u = __float_as_uint(f);
    u += 0x7fffu + ((u >> 16) & 1u);
    return (u16)(u >> 16);
}

__device__ __forceinline__ float bf2f(u16 b) {
    return __uint_as_float(((unsigned int)b) << 16);
}

// h[b,v,:] = x[b,(v + SEQ - vs[b]) % SEQ, :]
__global__ void k_permute(const float* __restrict__ x, const int* __restrict__ vs,
                          float* __restrict__ h) {
    int idx = blockIdx.x * blockDim.x + threadIdx.x;
    if (idx >= MTOK * DMODEL) return;
    int d  = idx % DMODEL;
    int mv = idx / DMODEL;
    int v  = mv % SEQ;
    int b  = mv / SEQ;
    int src = (v + SEQ - vs[b]) % SEQ;
    h[idx] = x[(b * SEQ + src) * DMODEL + d];
}

// fp32 -> bf16, 4/thread
__global__ void k_f2bf(const float* __restrict__ src, u16* __restrict__ dst, int n) {
    int i = (blockIdx.x * blockDim.x + threadIdx.x) * 4;
    if (i >= n) return;
    float4 v = *(const float4*)(src + i);
    ushort4 o;
    o.x = f2bf(v.x); o.y = f2bf(v.y); o.z = f2bf(v.z); o.w = f2bf(v.w);
    *(ushort4*)(dst + i) = o;
}

// xp_w [4][72][1280] fp32 -> [4][80][1280] bf16, rows 72..79 of each layer zeroed
__global__ void k_f2bf_pad4(const float* __restrict__ src, u16* __restrict__ dst) {
    int i = (blockIdx.x * blockDim.x + threadIdx.x) * 4;
    if (i >= NLAYER * NDBLP * DINNER) return;
    int layer = i / (NDBLP * DINNER);
    int rem   = i % (NDBLP * DINNER);
    int row   = rem / DINNER;
    int col   = rem % DINNER;
    ushort4 o = make_ushort4(0, 0, 0, 0);
    if (row < NDBL) {
        float4 v = *(const float4*)(src + (size_t)layer * NDBL * DINNER
                                        + (size_t)row * DINNER + col);
        o.x = f2bf(v.x); o.y = f2bf(v.y); o.z = f2bf(v.z); o.w = f2bf(v.w);
    }
    *(ushort4*)(dst + i) = o;
}

// dtw [4][1280][40] fp32 -> [4][1280][64] bf16, cols 40..63 zeroed
__global__ void k_f2bf_dtw(const float* __restrict__ src, u16* __restrict__ dst) {
    int i = blockIdx.x * blockDim.x + threadIdx.x;
    if (i >= NLAYER * DINNER * DTKP) return;
    int c  = i % DTKP;
    int ld = i / DTKP;          // layer*1280 + d
    u16 o = 0;
    if (c < DTRANK) o = f2bf(src[(size_t)ld * DTRANK + c]);
    dst[i] = o;
}

// one wave per token: xn_bf16 = h * rsqrt(mean(h^2)+eps) * w
__global__ __launch_bounds__(64)
void k_rmsnorm(const float* __restrict__ h, const float* __restrict__ w,
               u16* __restrict__ xn) {
    int m = blockIdx.x;
    int t = threadIdx.x;
    const float* row = h + (size_t)m * DMODEL;
    float ss = 0.f;
    for (int d = t; d < DMODEL; d += 64) { float v = row[d]; ss += v * v; }
    #pragma unroll
    for (int o = 32; o > 0; o >>= 1) ss += __shfl_xor(ss, o, 64);
    float sc = rsqrtf(ss / DMODEL + 1e-5f);
    u16* out = xn + (size_t)m * DMODEL;
    for (int d = t; d < DMODEL; d += 64) out[d] = f2bf(row[d] * sc * w[d]);
}

// 128x128-tile bf16 MFMA GEMM: out[m,n] = sum_k A[m,k]*W[n,k].
// If Cb != nullptr writes bf16 to Cb, else f32 (+resid) to Cf.
__global__ __launch_bounds__(256)
void k_mfma(const u16* __restrict__ A, int lda,
            const u16* __restrict__ W,
            const float* __restrict__ resid,
            float* __restrict__ Cf, u16* __restrict__ Cb,
            int N, int K) {
    __shared__ u16 As[128 * 32];
    __shared__ u16 Bs[128 * 32];
    const int t = threadIdx.x;
    const int w = t >> 6, l = t & 63;
    const int lane15 = l & 15, quad = l >> 4;
    const int wm = w >> 1, wn = w & 1;
    const int m0 = blockIdx.y * 128, n0 = blockIdx.x * 128;

    f32x4 acc[4][4];
    #pragma unroll
    for (int i = 0; i < 4; ++i)
        #pragma unroll
        for (int j = 0; j < 4; ++j)
            acc[i][j] = (f32x4){0.f, 0.f, 0.f, 0.f};

    for (int k0 = 0; k0 < K; k0 += 32) {
        __syncthreads();
        #pragma unroll
        for (int q = 0; q < 2; ++q) {
            int c = q * 256 + t;
            const u16* ga = A + (size_t)(m0 + (c >> 2)) * lda + k0 + (c & 3) * 8;
            __builtin_amdgcn_global_load_lds(
                (const __attribute__((address_space(1))) void*)ga,
                (__attribute__((address_space(3))) void*)&As[c * 8], 16, 0, 0);
            const u16* gb = W + (size_t)(n0 + (c >> 2)) * K + k0 + (c & 3) * 8;
            __builtin_amdgcn_global_load_lds(
                (const __attribute__((address_space(1))) void*)gb,
                (__attribute__((address_space(3))) void*)&Bs[c * 8], 16, 0, 0);
        }
        __syncthreads();

        bf16x8 af[4], bfrag[4];
        #pragma unroll
        for (int i = 0; i < 4; ++i)
            af[i] = *(const bf16x8*)&As[(wm * 64 + i * 16 + lane15) * 32 + quad * 8];
        #pragma unroll
        for (int j = 0; j < 4; ++j)
            bfrag[j] = *(const bf16x8*)&Bs[(wn * 64 + j * 16 + lane15) * 32 + quad * 8];
        #pragma unroll
        for (int i = 0; i < 4; ++i)
            #pragma unroll
            for (int j = 0; j < 4; ++j)
                acc[i][j] = __builtin_amdgcn_mfma_f32_16x16x32_bf16(
                    af[i], bfrag[j], acc[i][j], 0, 0, 0);
    }

    #pragma unroll
    for (int i = 0; i < 4; ++i) {
        #pragma unroll
        for (int r = 0; r < 4; ++r) {
            int row = m0 + wm * 64 + i * 16 + quad * 4 + r;
            #pragma unroll
            for (int j = 0; j < 4; ++j) {
                int col = n0 + wn * 64 + j * 16 + lane15;
                size_t idx = (size_t)row * N + col;
                if (Cb) {
                    Cb[idx] = f2bf(acc[i][j][r]);
                } else {
                    float v = acc[i][j][r];
                    if (resid) v += resid[idx];
                    Cf[idx] = v;
                }
            }
        }
    }
}

// 64x64-tile bf16 MFMA GEMM, f32 out + resid (out_proj)
__global__ __launch_bounds__(256)
void k_mfma64(const u16* __restrict__ A, int lda,
              const u16* __restrict__ W,
              const float* __restrict__ resid,
              float* __restrict__ C, int N, int K) {
    __shared__ u16 As[64 * 32];
    __shared__ u16 Bs[64 * 32];
    const int t = threadIdx.x;
    const int w = t >> 6, l = t & 63;
    const int lane15 = l & 15, quad = l >> 4;
    const int wm = w >> 1, wn = w & 1;
    const int m0 = blockIdx.y * 64, n0 = blockIdx.x * 64;

    f32x4 acc[2][2];
    #pragma unroll
    for (int i = 0; i < 2; ++i)
        #pragma unroll
        for (int j = 0; j < 2; ++j)
            acc[i][j] = (f32x4){0.f, 0.f, 0.f, 0.f};

    for (int k0 = 0; k0 < K; k0 += 32) {
        __syncthreads();
        {
            int c = t;
            const u16* ga = A + (size_t)(m0 + (c >> 2)) * lda + k0 + (c & 3) * 8;
            __builtin_amdgcn_global_load_lds(
                (const __attribute__((address_space(1))) void*)ga,
                (__attribute__((address_space(3))) void*)&As[c * 8], 16, 0, 0);
            const u16* gb = W + (size_t)(n0 + (c >> 2)) * K + k0 + (c & 3) * 8;
            __builtin_amdgcn_global_load_lds(
                (const __attribute__((address_space(1))) void*)gb,
                (__attribute__((address_space(3))) void*)&Bs[c * 8], 16, 0, 0);
        }
        __syncthreads();

        bf16x8 af[2], bfrag[2];
        #pragma unroll
        for (int i = 0; i < 2; ++i)
            af[i] = *(const bf16x8*)&As[(wm * 32 + i * 16 + lane15) * 32 + quad * 8];
        #pragma unroll
        for (int j = 0; j < 2; ++j)
            bfrag[j] = *(const bf16x8*)&Bs[(wn * 32 + j * 16 + lane15) * 32 + quad * 8];
        #pragma unroll
        for (int i = 0; i < 2; ++i)
            #pragma unroll
            for (int j = 0; j < 2; ++j)
                acc[i][j] = __builtin_amdgcn_mfma_f32_16x16x32_bf16(
                    af[i], bfrag[j], acc[i][j], 0, 0, 0);
    }

    #pragma unroll
    for (int i = 0; i < 2; ++i) {
        #pragma unroll
        for (int r = 0; r < 4; ++r) {
            int row = m0 + wm * 32 + i * 16 + quad * 4 + r;
            #pragma unroll
            for (int j = 0; j < 2; ++j) {
                int col = n0 + wn * 32 + j * 16 + lane15;
                size_t idx = (size_t)row * N + col;
                float v = acc[i][j][r];
                if (resid) v += resid[idx];
                C[idx] = v;
            }
        }
    }
}

// dt GEMM: delta[m,d] = softplus(sum_k dtA[m,k]*dtwb[d,k] + dtb[d]).
// 64x64 tile, K=64 (2 k-iters). Grid (1280/64, 1920/64) = 600 blocks.
__global__ __launch_bounds__(256)
void k_dtgemm(const u16* __restrict__ dtA, const u16* __restrict__ dtwb,
              const float* __restrict__ dtb, float* __restrict__ delta) {
    __shared__ u16 As[64 * 32];
    __shared__ u16 Bs[64 * 32];
    const int t = threadIdx.x;
    const int w = t >> 6, l = t & 63;
    const int lane15 = l & 15, quad = l >> 4;
    const int wm = w >> 1, wn = w & 1;
    const int m0 = blockIdx.y * 64, n0 = blockIdx.x * 64;

    f32x4 acc[2][2];
    #pragma unroll
    for (int i = 0; i < 2; ++i)
        #pragma unroll
        for (int j = 0; j < 2; ++j)
            acc[i][j] = (f32x4){0.f, 0.f, 0.f, 0.f};

    #pragma unroll
    for (int k0 = 0; k0 < DTKP; k0 += 32) {
        __syncthreads();
        {
            int c = t;
            const u16* ga = dtA + (size_t)(m0 + (c >> 2)) * DTKP + k0 + (c & 3) * 8;
            __builtin_amdgcn_global_load_lds(
                (const __attribute__((address_space(1))) void*)ga,
                (__attribute__((address_space(3))) void*)&As[c * 8], 16, 0, 0);
            const u16* gb = dtwb + (size_t)(n0 + (c >> 2)) * DTKP + k0 + (c & 3) * 8;
            __builtin_amdgcn_global_load_lds(
                (const __attribute__((address_space(1))) void*)gb,
                (__attribute__((address_space(3))) void*)&Bs[c * 8], 16, 0, 0);
        }
        __syncthreads();

        bf16x8 af[2], bfrag[2];
        #pragma unroll
        for (int i = 0; i < 2; ++i)
            af[i] = *(const bf16x8*)&As[(wm * 32 + i * 16 + lane15) * 32 + quad * 8];
        #pragma unroll
        for (int j = 0; j < 2; ++j)
            bfrag[j] = *(const bf16x8*)&Bs[(wn * 32 + j * 16 + lane15) * 32 + quad * 8];
        #pragma unroll
        for (int i = 0; i < 2; ++i)
            #pragma unroll
            for (int j = 0; j < 2; ++j)
                acc[i][j] = __builtin_amdgcn_mfma_f32_16x16x32_bf16(
                    af[i], bfrag[j], acc[i][j], 0, 0, 0);
    }

    #pragma unroll
    for (int i = 0; i < 2; ++i) {
        #pragma unroll
        for (int r = 0; r < 4; ++r) {
            int row = m0 + wm * 32 + i * 16 + quad * 4 + r;
            #pragma unroll
            for (int j = 0; j < 2; ++j) {
                int col = n0 + wn * 32 + j * 16 + lane15;
                float v = acc[i][j][r] + dtb[col];
                v = (v > 20.f) ? v : log1pf(__expf(v));
                delta[(size_t)row * DINNER + col] = v;
            }
        }
    }
}

// causal depthwise conv + silu: one thread per (b,c); bf16 in/out
__global__ __launch_bounds__(256)
void k_conv(const u16* __restrict__ urb, const float* __restrict__ cw,
            const float* __restrict__ cb, u16* __restrict__ ubf) {
    int idx = blockIdx.x * 256 + threadIdx.x;   // b*DINNER + c
    int c = idx % DINNER;
    int b = idx / DINNER;
    const u16* up = urb + (size_t)(b * SEQ) * NPROJ + c;
    float xv[SEQ];
    #pragma unroll
    for (int v = 0; v < SEQ; ++v) xv[v] = bf2f(up[(size_t)v * NPROJ]);
    float w0 = cw[c * 4 + 0], w1 = cw[c * 4 + 1];
    float w2 = cw[c * 4 + 2], w3 = cw[c * 4 + 3];
    float bias = cb[c];
    u16* op = ubf + (size_t)(b * SEQ) * DINNER + c;
    float x0 = 0.f, x1 = 0.f, x2 = 0.f;
    #pragma unroll
    for (int v = 0; v < SEQ; ++v) {
        float x3 = xv[v];
        float o = bias + w0 * x0 + w1 * x1 + w2 * x2 + w3 * x3;
        op[(size_t)v * DINNER] = f2bf(siluf(o));
        x0 = x1; x1 = x2; x2 = x3;
    }
}

// x_proj: split-K bf16 MFMA. A=ubf [MTOK,DINNER], B=wbx [80,DINNER].
// Grid (KSEGS, MTOK/64), 256 thr. Writes fp32 partials dblp[seg][MTOK][80].
__global__ __launch_bounds__(256)
void k_xproj(const u16* __restrict__ ubf, const u16* __restrict__ wbx,
             float* __restrict__ dblp) {
    __shared__ u16 As[64 * 32];
    __shared__ u16 Bs[NDBLP * 32];
    const int t = threadIdx.x;
    const int w = t >> 6, l = t & 63;
    const int lane15 = l & 15, quad = l >> 4;
    const int seg = blockIdx.x;
    const int m0 = blockIdx.y * 64;
    const int kb = seg * KSEG;

    f32x4 acc[5];
    #pragma unroll
    for (int j = 0; j < 5; ++j) acc[j] = (f32x4){0.f, 0.f, 0.f, 0.f};

    for (int k0 = 0; k0 < KSEG; k0 += 32) {
        __syncthreads();
        {
            int c = t;
            const u16* ga = ubf + (size_t)(m0 + (c >> 2)) * DINNER + kb + k0 + (c & 3) * 8;
            __builtin_amdgcn_global_load_lds(
                (const __attribute__((address_space(1))) void*)ga,
                (__attribute__((address_space(3))) void*)&As[c * 8], 16, 0, 0);
            const u16* gb = wbx + (size_t)(c >> 2) * DINNER + kb + k0 + (c & 3) * 8;
            __builtin_amdgcn_global_load_lds(
                (const __attribute__((address_space(1))) void*)gb,
                (__attribute__((address_space(3))) void*)&Bs[c * 8], 16, 0, 0);
        }
        if (t < 64) {
            int c = 256 + t;
            const u16* gb = wbx + (size_t)(c >> 2) * DINNER + kb + k0 + (c & 3) * 8;
            __builtin_amdgcn_global_load_lds(
                (const __attribute__((address_space(1))) void*)gb,
                (__attribute__((address_space(3))) void*)&Bs[c * 8], 16, 0, 0);
        }
        __syncthreads();

        bf16x8 af = *(const bf16x8*)&As[(w * 16 + lane15) * 32 + quad * 8];
        #pragma unroll
        for (int j = 0; j < 5; ++j) {
            bf16x8 bfrag = *(const bf16x8*)&Bs[(j * 16 + lane15) * 32 + quad * 8];
            acc[j] = __builtin_amdgcn_mfma_f32_16x16x32_bf16(af, bfrag, acc[j], 0, 0, 0);
        }
    }

    float* outp = dblp + (size_t)seg * MTOK * NDBLP;
    #pragma unroll
    for (int r = 0; r < 4; ++r) {
        int row = m0 + w * 16 + quad * 4 + r;
        #pragma unroll
        for (int j = 0; j < 5; ++j) {
            int col = j * 16 + lane15;
            outp[(size_t)row * NDBLP + col] = acc[j][r];
        }
    }
}

// sum split-K partials of the dt-rank columns -> bf16 dtA [MTOK][64] (pad 0)
__global__ __launch_bounds__(256)
void k_dtprep(const float* __restrict__ dblp, u16* __restrict__ dtA) {
    int i = blockIdx.x * 256 + threadIdx.x;   // m*64 + c
    if (i >= MTOK * DTKP) return;
    int c = i % DTKP;
    int m = i / DTKP;
    u16 o = 0;
    if (c < DTRANK) {
        float s = 0.f;
        #pragma unroll
        for (int sg = 0; sg < KSEGS; ++sg)
            s += dblp[(size_t)sg * MTOK * NDBLP + (size_t)m * NDBLP + c];
        o = f2bf(s);
    }
    dtA[i] = o;
}

// selective scan, one thread per (b,d); delta precomputed; inputs prefetched.
__global__ __launch_bounds__(256)
void k_scan(const u16* __restrict__ ubf, const u16* __restrict__ urb,
            const float* __restrict__ dblp, const float* __restrict__ delta,
            const float* __restrict__ A_log, const float* __restrict__ Dsk,
            u16* __restrict__ y) {
    __shared__ float BC[SEQ][2 * DSTATE];
    const int b  = blockIdx.x / (DINNER / 256);
    const int dc = blockIdx.x % (DINNER / 256);
    const int d  = dc * 256 + threadIdx.x;

    // stage summed B,C (split-K partials)
    for (int t = threadIdx.x; t < SEQ * 2 * DSTATE; t += 256) {
        int v = t >> 5, s = t & 31;
        float acc = 0.f;
        #pragma unroll
        for (int sg = 0; sg < KSEGS; ++sg)
            acc += dblp[(size_t)sg * MTOK * NDBLP + (size_t)(b * SEQ + v) * NDBLP + DTRANK + s];
        BC[v][s] = acc;
    }
    __syncthreads();

    // prefetch per-channel sequences (independent coalesced loads)
    float dl[SEQ], uu[SEQ], rr[SEQ];
    #pragma unroll
    for (int v = 0; v < SEQ; ++v)
        dl[v] = delta[(size_t)(b * SEQ + v) * DINNER + d];
    #pragma unroll
    for (int v = 0; v < SEQ; ++v)
        uu[v] = bf2f(ubf[(size_t)(b * SEQ + v) * DINNER + d]);
    #pragma unroll
    for (int v = 0; v < SEQ; ++v)
        rr[v] = bf2f(urb[(size_t)(b * SEQ + v) * NPROJ + DINNER + d]);

    float Ar[DSTATE];
    #pragma unroll
    for (int s = 0; s < DSTATE; ++s) Ar[s] = -__expf(A_log[(size_t)d * DSTATE + s]);
    float dsk = Dsk[d];
    float st[DSTATE];
    #pragma unroll
    for (int s = 0; s < DSTATE; ++s) st[s] = 0.f;

    u16* yp = y + (size_t)(b * SEQ) * DINNER + d;

    #pragma unroll
    for (int v = 0; v < SEQ; ++v) {
        float dlt = dl[v];
        float du  = dlt * uu[v];
        float ya0 = 0.f, ya1 = 0.f, ya2 = 0.f, ya3 = 0.f;
        #pragma unroll
        for (int s = 0; s < DSTATE; s += 4) {
            float dA0 = __expf(dlt * Ar[s + 0]);
            float dA1 = __expf(dlt * Ar[s + 1]);
            float dA2 = __expf(dlt * Ar[s + 2]);
            float dA3 = __expf(dlt * Ar[s + 3]);
            st[s + 0] = dA0 * st[s + 0] + du * BC[v][s + 0];
            st[s + 1] = dA1 * st[s + 1] + du * BC[v][s + 1];
            st[s + 2] = dA2 * st[s + 2] + du * BC[v][s + 2];
            st[s + 3] = dA3 * st[s + 3] + du * BC[v][s + 3];
            ya0 += st[s + 0] * BC[v][DSTATE + s + 0];
            ya1 += st[s + 1] * BC[v][DSTATE + s + 1];
            ya2 += st[s + 2] * BC[v][DSTATE + s + 2];
            ya3 += st[s + 3] * BC[v][DSTATE + s + 3];
        }
        float ya = (ya0 + ya1) + (ya2 + ya3);
        yp[(size_t)v * DINNER] = f2bf((ya + uu[v] * dsk) * siluf(rr[v]));
    }
}

// final rmsnorm fused with reverse permutation
__global__ __launch_bounds__(64)
void k_final(const float* __restrict__ h, const int* __restrict__ vs,
             const float* __restrict__ w, float* __restrict__ out) {
    int mv = blockIdx.x;
    int v = mv % SEQ, b = mv / SEQ;
    int src = (v + vs[b]) % SEQ;
    const float* row = h + (size_t)(b * SEQ + src) * DMODEL;
    int t = threadIdx.x;
    float ss = 0.f;
    for (int d = t; d < DMODEL; d += 64) { float x = row[d]; ss += x * x; }
    #pragma unroll
    for (int o = 32; o > 0; o >>= 1) ss += __shfl_xor(ss, o, 64);
    float sc = rsqrtf(ss / DMODEL + 1e-5f);
    float* op = out + (size_t)mv * DMODEL;
    for (int d = t; d < DMODEL; d += 64) op[d] = row[d] * sc * w[d];
}

extern "C" void kernel_launch(void* const* d_in, const int* in_sizes, int n_in,
                              void* d_out, int out_size, void* d_ws, size_t ws_size,
                              hipStream_t stream) {
    const float* x      = (const float*)d_in[0];
    const int*   vs     = (const int*)d_in[1];
    const float* norm_w = (const float*)d_in[2];
    const float* in_w   = (const float*)d_in[3];
    const float* conv_w = (const float*)d_in[4];
    const float* conv_b = (const float*)d_in[5];
    const float* xp_w   = (const float*)d_in[6];
    const float* dt_w   = (const float*)d_in[7];
    const float* dt_b   = (const float*)d_in[8];
    const float* A_log  = (const float*)d_in[9];
    const float* Dsk    = (const float*)d_in[10];
    const float* out_w  = (const float*)d_in[11];
    const float* nfw    = (const float*)d_in[12];
    float* out = (float*)d_out;

    char* p = (char*)d_ws;
    float* h     = (float*)p; p += (size_t)MTOK * DMODEL * 4;
    u16*   xn    = (u16*)p;   p += (size_t)MTOK * DMODEL * 2;
    u16*   urb   = (u16*)p;   p += (size_t)MTOK * NPROJ * 2;
    u16*   ubf   = (u16*)p;   p += (size_t)MTOK * DINNER * 2;
    float* dblp  = (float*)p; p += (size_t)KSEGS * MTOK * NDBLP * 4;
    u16*   dtA   = (u16*)p;   p += (size_t)MTOK * DTKP * 2;
    float* delta = (float*)p; p += (size_t)MTOK * DINNER * 4;
    u16*   y     = (u16*)p;   p += (size_t)MTOK * DINNER * 2;
    u16*   wbi4  = (u16*)p;   p += (size_t)NLAYER * NPROJ * DMODEL * 2;
    u16*   wbo4  = (u16*)p;   p += (size_t)NLAYER * DMODEL * DINNER * 2;
    u16*   wbx4  = (u16*)p;   p += (size_t)NLAYER * NDBLP * DINNER * 2;
    u16*   wdt4  = (u16*)p;   p += (size_t)NLAYER * DINNER * DTKP * 2;

    // hoisted weight conversions (once per call)
    k_f2bf<<<(NLAYER * NPROJ * DMODEL / 4 + 255) / 256, 256, 0, stream>>>(
        in_w, wbi4, NLAYER * NPROJ * DMODEL);
    k_f2bf<<<(NLAYER * DMODEL * DINNER / 4 + 255) / 256, 256, 0, stream>>>(
        out_w, wbo4, NLAYER * DMODEL * DINNER);
    k_f2bf_pad4<<<(NLAYER * NDBLP * DINNER / 4 + 255) / 256, 256, 0, stream>>>(
        xp_w, wbx4);
    k_f2bf_dtw<<<(NLAYER * DINNER * DTKP + 255) / 256, 256, 0, stream>>>(
        dt_w, wdt4);

    k_permute<<<(MTOK * DMODEL + 255) / 256, 256, 0, stream>>>(x, vs, h);

    for (int l = 0; l < NLAYER; ++l) {
        k_rmsnorm<<<MTOK, 64, 0, stream>>>(h, norm_w + (size_t)l * DMODEL, xn);

        k_mfma<<<dim3(NPROJ / 128, MTOK / 128), 256, 0, stream>>>(
            xn, DMODEL, wbi4 + (size_t)l * NPROJ * DMODEL, nullptr,
            nullptr, urb, NPROJ, DMODEL);

        k_conv<<<BATCH * DINNER / 256, 256, 0, stream>>>(
            urb, conv_w + (size_t)l * DINNER * DCONV, conv_b + (size_t)l * DINNER, ubf);

        k_xproj<<<dim3(KSEGS, MTOK / 64), 256, 0, stream>>>(
            ubf, wbx4 + (size_t)l * NDBLP * DINNER, dblp);

        k_dtprep<<<(MTOK * DTKP + 255) / 256, 256, 0, stream>>>(dblp, dtA);

        k_dtgemm<<<dim3(DINNER / 64, MTOK / 64), 256, 0, stream>>>(
            dtA, wdt4 + (size_t)l * DINNER * DTKP,
            dt_b + (size_t)l * DINNER, delta);

        k_scan<<<BATCH * (DINNER / 256), 256, 0, stream>>>(
            ubf, urb, dblp, delta,
            A_log + (size_t)l * DINNER * DSTATE, Dsk + (size_t)l * DINNER, y);

        k_mfma64<<<dim3(DMODEL / 64, MTOK / 64), 256, 0, stream>>>(
            y, DINNER, wbo4 + (size_t)l * DMODEL * DINNER, h, h, DMODEL, DINNER);
    }

    k_final<<<MTOK, 64, 0, stream>>>(h, vs, nfw, out);
}